// Round 14
// baseline (128.241 us; speedup 1.0000x reference)
//
#include <hip/hip_runtime.h>
#include <hip/hip_fp16.h>

// Problem constants
#define B_IMG 8
#define C_IN  16
#define COUT  64
#define H0    36
#define H1    6
#define NB    6
#define NNODE 43
// OH=OW=16; output [8][64][16][16]

typedef float f32x2 __attribute__((ext_vector_type(2)));

__device__ __forceinline__ float sigf(float v) { return 1.0f / (1.0f + __expf(-v)); }
__device__ __forceinline__ float4 sig4(float4 a) {
    return make_float4(sigf(a.x), sigf(a.y), sigf(a.z), sigf(a.w));
}

// Single-pixel 6-bit multilinear interp from an LDS delta table (wave-uniform
// broadcast reads). 32-float working tree -> ~70 VGPR total working set so the
// kernel fits the 85-VGPR cap for 6 waves/EU (3 blocks/CU) WITHOUT spilling.
// g[0] contracts the MSB ... g[5] the LSB (matches reference einsum order).
__device__ __forceinline__ float lut_contract_lds(const float* tb, const float g[NB]) {
    f32x2 v[16];
    const float4* t4 = (const float4*)tb;
    const float g0 = g[0];
#pragma unroll
    for (int q = 0; q < 8; ++q) {
        const float4 lo = t4[q];
        const float4 dd = t4[q + 8];
        v[2*q]   = (f32x2){lo.x, lo.y} + (f32x2){dd.x, dd.y} * g0;
        v[2*q+1] = (f32x2){lo.z, lo.w} + (f32x2){dd.z, dd.w} * g0;
    }
#pragma unroll
    for (int i = 1; i < 5; ++i) {
        const int vh = 16 >> i;
        const float gi = g[i];
#pragma unroll
        for (int r = 0; r < vh; ++r)
            v[r] += (v[r + vh] - v[r]) * gi;
    }
    return v[0].x + (v[0].y - v[0].x) * g[5];
}

// Block = (channel t, image img): 512 threads = 8 waves, 256 pixels.
// LDS ~37 KB + VGPR<=85 (launch_bounds 512,6) -> 3 blocks/CU co-resident:
// staging/A/B/C phases of different blocks overlap, hiding latency at the
// observed low core clock.
__global__ __launch_bounds__(512, 6) void lutone_kernel(
    const float* __restrict__ x,
    const int*   __restrict__ idx0,
    const float* __restrict__ t0,
    const int*   __restrict__ idx1,
    const float* __restrict__ t1,
    const int*   __restrict__ idx2,
    const float* __restrict__ t2,
    float*       __restrict__ out)
{
    __shared__ float   tblL[NNODE*64];          // sigmoid'd delta: lo[32]|dd[32]
    __shared__ __half  h0s[H0*256];             // fp16 activations (18 KB)
    __shared__ float   h1s[H1*256];
    __shared__ __align__(16) int metaL[H0*8];   // per node: 6 x ((off+66)|(rem<<20))
    __shared__ int     idx1L[H1*NB];
    __shared__ int     idx2L[NB];

    const int tid  = threadIdx.x;
    const int w    = tid >> 6;
    const int lane = tid & 63;
    const int t    = blockIdx.x & 63;
    const int img  = blockIdx.x >> 6;

    // ---- issue all staging loads first (latency overlaps the ALU below) ----
    float4 aLo = {}, aHi = {};
    const bool haveT = tid < NNODE*8;
    int nodeT = 0, qT = 0;
    if (haveT) {
        nodeT = tid >> 3; qT = tid & 7;
        const float* src = (nodeT < H0)      ? t0 + ((size_t)t*H0 + nodeT)*64
                         : (nodeT < H0+H1)   ? t1 + ((size_t)t*H1 + nodeT - H0)*64
                                             : t2 + (size_t)t*64;
        const float4* s4 = (const float4*)src;
        aLo = s4[qT]; aHi = s4[qT + 8];
    }
    int rawM = 0;
    if (tid < H0*NB) rawM = idx0[(size_t)t*(H0*NB) + tid];
    if (tid < H1*NB) idx1L[tid] = idx1[(size_t)t*(H1*NB) + tid];
    if (tid < NB)    idx2L[tid] = idx2[(size_t)t*NB + tid];

    // ---- per-lane pixel geometry (independent ALU, overlaps loads) ----
    int base[4], vmask[4];
#pragma unroll
    for (int c = 0; c < 4; ++c) {
        const int p  = (c << 6) + lane;
        const int oh = p >> 4, ow = p & 15;
        base[c] = img*16384 + oh*64 + ow*2;            // oh2*32 + ow2
        const int hm = 0x1F ^ ((oh == 0) ? 0x03 : 0) ^ ((oh == 15) ? 0x10 : 0);
        const int wm = 0x1F ^ ((ow == 0) ? 0x03 : 0) ^ ((ow == 15) ? 0x10 : 0);
        int vm = 0;
#pragma unroll
        for (int kh = 0; kh < 5; ++kh)
            vm |= ((hm >> kh) & 1) ? (wm << (5*kh)) : 0;
        vmask[c] = vm;
    }

    // ---- finish staging: sigmoid tables + decoded meta into LDS ----
    if (haveT) {
        float4* tbl4 = (float4*)tblL;
        const float4 lo = sig4(aLo);
        const float4 hi = sig4(aHi);
        tbl4[nodeT*16 + qT]     = lo;
        tbl4[nodeT*16 + 8 + qT] = make_float4(hi.x - lo.x, hi.y - lo.y,
                                              hi.z - lo.z, hi.w - lo.w);
    }
    if (tid < H0*NB) {
        const int n  = tid / 6, i = tid - 6*n;
        const int c2  = rawM / 25;
        const int rem = rawM - 25*c2;                  // kh*5 + kw
        const int kh  = rem / 5, kw = rem - 5*kh;
        const int off = c2*1024 + kh*32 + kw - 66;     // halo shift; off+66 >= 0
        metaL[n*8 + i] = (off + 66) | (rem << 20);
    }
    __syncthreads();

    // ---- used-node mask from LDS (broadcast reads) + node assignment ----
    unsigned long long umask = 0ull;
#pragma unroll
    for (int j = 0; j < H1*NB; ++j) umask |= 1ull << idx1L[j];

    int myn0 = -1, myn1 = -1, myn2 = -1, myn3 = -1, myn4 = -1;
    {
        int cnt = 0;
        for (int n = 0; n < H0; ++n) {
            if (!((umask >> n) & 1ull)) continue;
            const int slot = cnt++;
            if ((slot & 7) != w) continue;
            const int k = slot >> 3;
            if      (k == 0) myn0 = n;
            else if (k == 1) myn1 = n;
            else if (k == 2) myn2 = n;
            else if (k == 3) myn3 = n;
            else             myn4 = n;
        }
    }

    // ---- phase A: layer 0; single-px contractions, 4 chunks per node ----
#define NODE_A(NN)                                                            \
    if ((NN) >= 0) {                                                          \
        const int4* mp = (const int4*)(metaL + (NN)*8);                       \
        const int4 mA = mp[0];                                                \
        const int2 mB = ((const int2*)mp)[2];                                 \
        const int pk_[NB] = {mA.x, mA.y, mA.z, mA.w, mB.x, mB.y};             \
        _Pragma("unroll")                                                     \
        for (int c = 0; c < 4; ++c) {                                         \
            float g[NB];                                                      \
            _Pragma("unroll")                                                 \
            for (int i = 0; i < NB; ++i) {                                    \
                const int off = (pk_[i] & 0xFFFFF) - 66;                      \
                const int rem = pk_[i] >> 20;                                 \
                const bool ok = ((vmask[c] >> rem) & 1) != 0;                 \
                const float v = x[ok ? (base[c] + off) : 0];                  \
                g[i] = ok ? v : 0.0f;                                         \
            }                                                                 \
            const float r = lut_contract_lds(tblL + (NN)*64, g);              \
            h0s[(NN)*256 + (c << 6) + lane] = __float2half(r);                \
        }                                                                     \
    }
    NODE_A(myn0)
    NODE_A(myn1)
    NODE_A(myn2)
    NODE_A(myn3)
    NODE_A(myn4)
#undef NODE_A
    __syncthreads();

    // ---- phase B: layer 1; 24 chunk-units over 8 waves (<=3 each) ----
    if (w < H1) {
        const int* i1 = idx1L + w*NB;
        const int s0 = i1[0], s1 = i1[1], s2 = i1[2];
        const int s3 = i1[3], s4 = i1[4], s5 = i1[5];
#pragma unroll
        for (int c = 0; c < 3; ++c) {
            const int px = (c << 6) + lane;
            float g[NB];
            g[0] = __half2float(h0s[s0*256 + px]);
            g[1] = __half2float(h0s[s1*256 + px]);
            g[2] = __half2float(h0s[s2*256 + px]);
            g[3] = __half2float(h0s[s3*256 + px]);
            g[4] = __half2float(h0s[s4*256 + px]);
            g[5] = __half2float(h0s[s5*256 + px]);
            h1s[w*256 + px] = lut_contract_lds(tblL + (H0 + w)*64, g);
        }
    } else {
        const int nb0 = (w == 6) ? 0 : 3;
        const int px  = (3 << 6) + lane;
#pragma unroll
        for (int k = 0; k < 3; ++k) {
            const int n = nb0 + k;
            const int* i1 = idx1L + n*NB;
            float g[NB];
#pragma unroll
            for (int i = 0; i < NB; ++i) g[i] = __half2float(h0s[i1[i]*256 + px]);
            h1s[n*256 + px] = lut_contract_lds(tblL + (H0 + n)*64, g);
        }
    }
    __syncthreads();

    // ---- phase C: layer 2; waves 0..3 take one 64-px chunk each ----
    if (w < 4) {
        const int px = (w << 6) + lane;
        float g[NB];
#pragma unroll
        for (int i = 0; i < NB; ++i) g[i] = h1s[idx2L[i]*256 + px];
        out[((size_t)img*COUT + t)*256 + px] =
            lut_contract_lds(tblL + (H0 + H1)*64, g);
    }
}

extern "C" void kernel_launch(void* const* d_in, const int* in_sizes, int n_in,
                              void* d_out, int out_size, void* d_ws, size_t ws_size,
                              hipStream_t stream) {
    const float* x      = (const float*)d_in[0];
    const int*   idx0   = (const int*)  d_in[1];
    const float* table0 = (const float*)d_in[2];
    const int*   idx1   = (const int*)  d_in[3];
    const float* table1 = (const float*)d_in[4];
    const int*   idx2   = (const int*)  d_in[5];
    const float* table2 = (const float*)d_in[6];
    float* out = (float*)d_out;

    lutone_kernel<<<COUT * B_IMG, 512, 0, stream>>>(
        x, idx0, table0, idx1, table1, idx2, table2, out);
}

// Round 15
// 25.305 us; speedup vs baseline: 5.0678x; 5.0678x over previous
//
#include <hip/hip_runtime.h>
#include <hip/hip_fp16.h>

// Problem constants
#define B_IMG 8
#define C_IN  16
#define COUT  64
#define H0    36
#define H1    6
#define NB    6
#define NNODE 43
// OH=OW=16; output [8][64][16][16]

typedef float f32x2 __attribute__((ext_vector_type(2)));

__device__ __forceinline__ float sigf(float v) { return 1.0f / (1.0f + __expf(-v)); }
__device__ __forceinline__ float4 sig4(float4 a) {
    return make_float4(sigf(a.x), sigf(a.y), sigf(a.z), sigf(a.w));
}

// 6-bit multilinear interp from an fp16 LDS delta table (wave-uniform
// broadcast reads: 8 x ds_read_b128 per call vs 16 for fp32 tables).
// Levels 0-1 in packed fp16 (v_pk_fma_f16), levels 2-5 in fp32.
// g[0] contracts the MSB ... g[5] the LSB (matches reference einsum order).
__device__ __forceinline__ float lut_contract_h(const __half* tb, const float g[NB]) {
    const __half2* lo2 = (const __half2*)tb;       // 16 half2 = lo[32]
    const __half2* dd2 = lo2 + 16;                 // 16 half2 = dd[32]
    const __half2 g0 = __float2half2_rn(g[0]);
    const __half2 g1 = __float2half2_rn(g[1]);
    __half2 u[16];
#pragma unroll
    for (int j = 0; j < 16; ++j) u[j] = __hfma2(dd2[j], g0, lo2[j]);   // level 0
    __half2 s[8];
#pragma unroll
    for (int j = 0; j < 8; ++j)                                        // level 1
        s[j] = __hfma2(__hsub2(u[j + 8], u[j]), g1, u[j]);
    f32x2 a[8];
#pragma unroll
    for (int j = 0; j < 8; ++j)
        a[j] = (f32x2){__low2float(s[j]), __high2float(s[j])};
    const float g2 = g[2], g3 = g[3], g4 = g[4];
#pragma unroll
    for (int j = 0; j < 4; ++j) a[j] += (a[j + 4] - a[j]) * g2;        // level 2
#pragma unroll
    for (int j = 0; j < 2; ++j) a[j] += (a[j + 2] - a[j]) * g3;        // level 3
    a[0] += (a[1] - a[0]) * g4;                                        // level 4
    return a[0].x + (a[0].y - a[0].x) * g[5];                          // level 5
}

// Single fused kernel: block = (channel t, image img), 512 threads = 8 waves,
// 256 pixels. fp16 tables + fp16 h0 in LDS (~31.5 KB total). Natural VGPR
// allocation (no min-waves: R14 showed forcing it spills catastrophically).
__global__ __launch_bounds__(512) void lutone_kernel(
    const float* __restrict__ x,
    const int*   __restrict__ idx0,
    const float* __restrict__ t0,
    const int*   __restrict__ idx1,
    const float* __restrict__ t1,
    const int*   __restrict__ idx2,
    const float* __restrict__ t2,
    float*       __restrict__ out)
{
    __shared__ __align__(16) __half tblH[NNODE*64];  // per node: lo[32]|dd[32]
    __shared__ __half h0s[H0*256];     // fp16 activations — bank 2-way, free
    __shared__ float  h1s[H1*256];
    __shared__ int    metaL[H0*NB*2];  // per (node,i): {off, rem}
    __shared__ int    idx1L[H1*NB];
    __shared__ int    idx2L[NB];

    const int tid  = threadIdx.x;
    const int w    = tid >> 6;
    const int lane = tid & 63;
    const int t    = blockIdx.x & 63;
    const int img  = blockIdx.x >> 6;

    // ---- stage sigmoid'd fp16 delta tables into LDS (344 items, 1 round) ----
    if (tid < NNODE*8) {
        const int node = tid >> 3, q = tid & 7;
        const float* src = (node < H0)      ? t0 + ((size_t)t*H0 + node)*64
                         : (node < H0+H1)   ? t1 + ((size_t)t*H1 + node - H0)*64
                                            : t2 + (size_t)t*64;
        const float4* s4 = (const float4*)src;
        const float4 lo = sig4(s4[q]);
        const float4 hi = sig4(s4[q + 8]);
        __half2* lp = (__half2*)(tblH + node*64 + 4*q);
        lp[0] = __float22half2_rn(make_float2(lo.x, lo.y));
        lp[1] = __float22half2_rn(make_float2(lo.z, lo.w));
        __half2* dp = (__half2*)(tblH + node*64 + 32 + 4*q);
        dp[0] = __float22half2_rn(make_float2(hi.x - lo.x, hi.y - lo.y));
        dp[1] = __float22half2_rn(make_float2(hi.z - lo.z, hi.w - lo.w));
    }
    // ---- decode idx0 -> LDS meta (one thread per (node,bit)) ----
    if (tid < H0*NB) {
        const int raw = idx0[(size_t)t*(H0*NB) + tid];
        const int c2  = raw / 25;
        const int rem = raw - 25*c2;                   // kh*5 + kw
        const int kh  = rem / 5, kw = rem - 5*kh;
        metaL[tid*2 + 0] = c2*1024 + kh*32 + kw - 66;  // -(2*32+2) halo shift
        metaL[tid*2 + 1] = rem;
    }
    if (tid < H1*NB) idx1L[tid] = idx1[(size_t)t*(H1*NB) + tid];
    if (tid < NB)    idx2L[tid] = idx2[(size_t)t*NB + tid];

    // ---- wave-uniform used-node mask (scalar pipe) ----
    const int* i1base = idx1 + t*(H1*NB);
    unsigned long long umask = 0ull;
#pragma unroll
    for (int j = 0; j < H1*NB; ++j) umask |= 1ull << i1base[j];

    // ---- per-lane pixel geometry: base addr + 25-bit (kh,kw) validity mask ----
    int base[4], vmask[4];
#pragma unroll
    for (int c = 0; c < 4; ++c) {
        const int p  = (c << 6) + lane;
        const int oh = p >> 4, ow = p & 15;
        base[c] = img*16384 + oh*64 + ow*2;            // oh2*32 + ow2
        const int hm = 0x1F ^ ((oh == 0) ? 0x03 : 0) ^ ((oh == 15) ? 0x10 : 0);
        const int wm = 0x1F ^ ((ow == 0) ? 0x03 : 0) ^ ((ow == 15) ? 0x10 : 0);
        int vm = 0;
#pragma unroll
        for (int kh = 0; kh < 5; ++kh)
            vm |= ((hm >> kh) & 1) ? (wm << (5*kh)) : 0;
        vmask[c] = vm;
    }

    // ---- this wave's node assignment (<=5 nodes, named regs: rule #20) ----
    int myn0 = -1, myn1 = -1, myn2 = -1, myn3 = -1, myn4 = -1;
    {
        int cnt = 0;
        for (int n = 0; n < H0; ++n) {
            if (!((umask >> n) & 1ull)) continue;
            const int slot = cnt++;
            if ((slot & 7) != w) continue;
            const int k = slot >> 3;
            if      (k == 0) myn0 = n;
            else if (k == 1) myn1 = n;
            else if (k == 2) myn2 = n;
            else if (k == 3) myn3 = n;
            else             myn4 = n;
        }
    }
    __syncthreads();   // tblH + metaL ready

    // ---- phase A: layer 0; 4 chunk-contractions per node ----
#define NODE_A(NN)                                                           \
    if ((NN) >= 0) {                                                         \
        const int4* mp = (const int4*)(metaL + (NN)*12);                     \
        const int4 ma = mp[0], mb = mp[1], mc = mp[2];                       \
        const int off_[NB] = {ma.x, ma.z, mb.x, mb.z, mc.x, mc.z};           \
        const int rem_[NB] = {ma.y, ma.w, mb.y, mb.w, mc.y, mc.w};           \
        _Pragma("unroll")                                                    \
        for (int c = 0; c < 4; ++c) {                                        \
            float g[NB];                                                     \
            _Pragma("unroll")                                                \
            for (int i = 0; i < NB; ++i) {                                   \
                const bool ok = ((vmask[c] >> rem_[i]) & 1) != 0;            \
                const float v = x[ok ? (base[c] + off_[i]) : 0];             \
                g[i] = ok ? v : 0.0f;                                        \
            }                                                                \
            const float r = lut_contract_h(tblH + (NN)*64, g);               \
            h0s[(NN)*256 + (c << 6) + lane] = __float2half(r);               \
        }                                                                    \
    }
    NODE_A(myn0)
    NODE_A(myn1)
    NODE_A(myn2)
    NODE_A(myn3)
    NODE_A(myn4)
#undef NODE_A
    __syncthreads();

    // ---- phase B: layer 1; 24 chunk-units over 8 waves (<=3 each) ----
    if (w < H1) {
        const int* i1 = idx1L + w*NB;
        const int s0 = i1[0], s1 = i1[1], s2 = i1[2];
        const int s3 = i1[3], s4 = i1[4], s5 = i1[5];
#pragma unroll
        for (int c = 0; c < 3; ++c) {
            const int px = (c << 6) + lane;
            float g[NB];
            g[0] = __half2float(h0s[s0*256 + px]);
            g[1] = __half2float(h0s[s1*256 + px]);
            g[2] = __half2float(h0s[s2*256 + px]);
            g[3] = __half2float(h0s[s3*256 + px]);
            g[4] = __half2float(h0s[s4*256 + px]);
            g[5] = __half2float(h0s[s5*256 + px]);
            h1s[w*256 + px] = lut_contract_h(tblH + (H0 + w)*64, g);
        }
    } else {
        const int nb0 = (w == 6) ? 0 : 3;
        const int px  = (3 << 6) + lane;
#pragma unroll
        for (int k = 0; k < 3; ++k) {
            const int n = nb0 + k;
            const int* i1 = idx1L + n*NB;
            float g[NB];
#pragma unroll
            for (int i = 0; i < NB; ++i) g[i] = __half2float(h0s[i1[i]*256 + px]);
            h1s[n*256 + px] = lut_contract_h(tblH + (H0 + n)*64, g);
        }
    }
    __syncthreads();

    // ---- phase C: layer 2; waves 0..3 take one 64-px chunk each ----
    if (w < 4) {
        const int px = (w << 6) + lane;
        float g[NB];
#pragma unroll
        for (int i = 0; i < NB; ++i) g[i] = h1s[idx2L[i]*256 + px];
        out[((size_t)img*COUT + t)*256 + px] =
            lut_contract_h(tblH + (H0 + H1)*64, g);
    }
}

extern "C" void kernel_launch(void* const* d_in, const int* in_sizes, int n_in,
                              void* d_out, int out_size, void* d_ws, size_t ws_size,
                              hipStream_t stream) {
    const float* x      = (const float*)d_in[0];
    const int*   idx0   = (const int*)  d_in[1];
    const float* table0 = (const float*)d_in[2];
    const int*   idx1   = (const int*)  d_in[3];
    const float* table1 = (const float*)d_in[4];
    const int*   idx2   = (const int*)  d_in[5];
    const float* table2 = (const float*)d_in[6];
    float* out = (float*)d_out;

    lutone_kernel<<<COUT * B_IMG, 512, 0, stream>>>(
        x, idx0, table0, idx1, table1, idx2, table2, out);
}

// Round 16
// 25.283 us; speedup vs baseline: 5.0723x; 1.0009x over previous
//
#include <hip/hip_runtime.h>
#include <hip/hip_fp16.h>

// Problem constants
#define B_IMG 8
#define C_IN  16
#define COUT  64
#define H0    36
#define H1    6
#define NB    6
#define NNODE 43
// OH=OW=16; output [8][64][16][16]

typedef float f32x2 __attribute__((ext_vector_type(2)));
typedef float f32x4 __attribute__((ext_vector_type(4)));

__device__ __forceinline__ float sigf(float v) { return 1.0f / (1.0f + __expf(-v)); }
__device__ __forceinline__ float4 sig4(float4 a) {
    return make_float4(sigf(a.x), sigf(a.y), sigf(a.z), sigf(a.w));
}

// 6-bit multilinear interp; table already in REGISTERS as f32x4 lo[8]|dd[8]
// (delta form). All-pk_fma_f32 tree; element e of v[q] holds index 4q+e:
// level0 uses g[0] (MSB), then bit4..bit0 via q-pairs then lane swizzle.
__device__ __forceinline__ float lut_tree(const f32x4 lo[8], const f32x4 dd[8],
                                          const float g[NB]) {
    f32x4 v[8];
    const float g0 = g[0];
#pragma unroll
    for (int q = 0; q < 8; ++q) v[q] = lo[q] + dd[q] * g0;      // level 0 (bit5)
    const float g1 = g[1], g2 = g[2], g3 = g[3];
#pragma unroll
    for (int q = 0; q < 4; ++q) v[q] += (v[q + 4] - v[q]) * g1; // bit4
#pragma unroll
    for (int q = 0; q < 2; ++q) v[q] += (v[q + 2] - v[q]) * g2; // bit3
    v[0] += (v[1] - v[0]) * g3;                                 // bit2
    f32x2 a = {v[0].x, v[0].y};
    const f32x2 b = {v[0].z, v[0].w};
    a += (b - a) * g[4];                                        // bit1
    return a.x + (a.y - a.x) * g[5];                            // bit0
}

// Load a 64-entry delta table from LDS into registers (16 x ds_read_b128).
__device__ __forceinline__ void load_tbl(const float* tb, f32x4 lo[8], f32x4 dd[8]) {
    const f32x4* t4 = (const f32x4*)tb;
#pragma unroll
    for (int q = 0; q < 8; ++q) { lo[q] = t4[q]; dd[q] = t4[q + 8]; }
}

// Block = (channel t, image img): 256 threads = 4 waves, 256 pixels.
// Phase A: wave owns ~6 layer-0 nodes; table PINNED in VGPRs across the 4
// pixel-chunks (asm barrier stops the compiler re-materializing the LDS
// reads per chunk — the R12 VGPR=64 pathology). Phases B/C: thread = pixel.
// LDS ~37 KB -> 3-4 blocks/CU co-resident.
__global__ __launch_bounds__(256) void lutone_kernel(
    const float* __restrict__ x,
    const int*   __restrict__ idx0,
    const float* __restrict__ t0,
    const int*   __restrict__ idx1,
    const float* __restrict__ t1,
    const int*   __restrict__ idx2,
    const float* __restrict__ t2,
    float*       __restrict__ out)
{
    __shared__ float  tblL[NNODE*64];  // sigmoid'd delta tables: lo[32]|dd[32]
    __shared__ __half h0s[H0*256];     // fp16 activations (18.4 KB)
    __shared__ float  h1s[H1*256];
    __shared__ int    metaL[H0*NB*2];  // per (node,i): {off, rem}
    __shared__ int    idx1L[H1*NB];
    __shared__ int    idx2L[NB];

    const int tid  = threadIdx.x;
    const int w    = tid >> 6;
    const int lane = tid & 63;
    const int t    = blockIdx.x & 63;
    const int img  = blockIdx.x >> 6;

    // ---- stage sigmoid'd fp32 delta tables into LDS (344 float4-pairs) ----
    {
        float4* tbl4 = (float4*)tblL;
        for (int e = tid; e < NNODE*8; e += 256) {
            const int node = e >> 3, q = e & 7;
            const float* src = (node < H0)      ? t0 + ((size_t)t*H0 + node)*64
                             : (node < H0+H1)   ? t1 + ((size_t)t*H1 + node - H0)*64
                                                : t2 + (size_t)t*64;
            const float4* s4 = (const float4*)src;
            const float4 lo = sig4(s4[q]);
            const float4 hi = sig4(s4[q + 8]);
            tbl4[node*16 + q]     = lo;
            tbl4[node*16 + 8 + q] = make_float4(hi.x - lo.x, hi.y - lo.y,
                                                hi.z - lo.z, hi.w - lo.w);
        }
    }
    // ---- decode idx0 -> LDS meta (one thread per (node,bit)) ----
    if (tid < H0*NB) {
        const int raw = idx0[(size_t)t*(H0*NB) + tid];
        const int c2  = raw / 25;
        const int rem = raw - 25*c2;                   // kh*5 + kw
        const int kh  = rem / 5, kw = rem - 5*kh;
        metaL[tid*2 + 0] = c2*1024 + kh*32 + kw - 66;  // -(2*32+2) halo shift
        metaL[tid*2 + 1] = rem;
    }
    if (tid < H1*NB) idx1L[tid] = idx1[(size_t)t*(H1*NB) + tid];
    if (tid < NB)    idx2L[tid] = idx2[(size_t)t*NB + tid];

    // ---- wave-uniform used-node mask (scalar pipe) ----
    const int* i1base = idx1 + t*(H1*NB);
    unsigned long long umask = 0ull;
#pragma unroll
    for (int j = 0; j < H1*NB; ++j) umask |= 1ull << i1base[j];

    // ---- per-lane pixel geometry for phase A (px = c*64 + lane) ----
    int base[4], vmask[4];
#pragma unroll
    for (int c = 0; c < 4; ++c) {
        const int p  = (c << 6) + lane;
        const int oh = p >> 4, ow = p & 15;
        base[c] = img*16384 + oh*64 + ow*2;            // oh2*32 + ow2
        const int hm = 0x1F ^ ((oh == 0) ? 0x03 : 0) ^ ((oh == 15) ? 0x10 : 0);
        const int wm = 0x1F ^ ((ow == 0) ? 0x03 : 0) ^ ((ow == 15) ? 0x10 : 0);
        int vm = 0;
#pragma unroll
        for (int kh = 0; kh < 5; ++kh)
            vm |= ((hm >> kh) & 1) ? (wm << (5*kh)) : 0;
        vmask[c] = vm;
    }

    // ---- this wave's node assignment (<=9 nodes, named regs: rule #20) ----
    int myn0=-1, myn1=-1, myn2=-1, myn3=-1, myn4=-1, myn5=-1, myn6=-1, myn7=-1, myn8=-1;
    {
        int cnt = 0;
        for (int n = 0; n < H0; ++n) {
            if (!((umask >> n) & 1ull)) continue;
            const int slot = cnt++;
            if ((slot & 3) != w) continue;
            switch (slot >> 2) {
                case 0: myn0 = n; break;
                case 1: myn1 = n; break;
                case 2: myn2 = n; break;
                case 3: myn3 = n; break;
                case 4: myn4 = n; break;
                case 5: myn5 = n; break;
                case 6: myn6 = n; break;
                case 7: myn7 = n; break;
                default: myn8 = n; break;
            }
        }
    }
    __syncthreads();   // tblL + metaL ready

    // ---- phase A: wave-owned nodes; table read ONCE, pinned across 4 chunks ----
#define NODE_A(NN)                                                           \
    if ((NN) >= 0) {                                                         \
        const int4* mp = (const int4*)(metaL + (NN)*12);                     \
        const int4 ma = mp[0], mb = mp[1], mc = mp[2];                       \
        const int off_[NB] = {ma.x, ma.z, mb.x, mb.z, mc.x, mc.z};           \
        const int rem_[NB] = {ma.y, ma.w, mb.y, mb.w, mc.y, mc.w};           \
        f32x4 lo[8], dd[8];                                                  \
        load_tbl(tblL + (NN)*64, lo, dd);                                    \
        _Pragma("unroll")                                                    \
        for (int q = 0; q < 8; ++q)                                          \
            asm volatile("" : "+v"(lo[q]), "+v"(dd[q]));  /* pin in VGPRs */ \
        _Pragma("unroll")                                                    \
        for (int c = 0; c < 4; ++c) {                                        \
            float g[NB];                                                     \
            _Pragma("unroll")                                                \
            for (int i = 0; i < NB; ++i) {                                   \
                const bool ok = ((vmask[c] >> rem_[i]) & 1) != 0;            \
                const float v = x[ok ? (base[c] + off_[i]) : 0];             \
                g[i] = ok ? v : 0.0f;                                        \
            }                                                                \
            const float r = lut_tree(lo, dd, g);                             \
            h0s[(NN)*256 + (c << 6) + lane] = __float2half(r);               \
        }                                                                    \
    }
    NODE_A(myn0)
    NODE_A(myn1)
    NODE_A(myn2)
    NODE_A(myn3)
    NODE_A(myn4)
    NODE_A(myn5)
    NODE_A(myn6)
    NODE_A(myn7)
    NODE_A(myn8)
#undef NODE_A
    __syncthreads();

    // ---- phase B: layer 1; thread = pixel, 6 sequential contractions ----
    {
#pragma unroll
        for (int n = 0; n < H1; ++n) {
            f32x4 lo[8], dd[8];
            load_tbl(tblL + (H0 + n)*64, lo, dd);
            const int* i1 = idx1L + n*NB;
            float g[NB];
#pragma unroll
            for (int i = 0; i < NB; ++i) g[i] = __half2float(h0s[i1[i]*256 + tid]);
            h1s[n*256 + tid] = lut_tree(lo, dd, g);
        }
    }
    __syncthreads();

    // ---- phase C: layer 2; thread = pixel ----
    {
        f32x4 lo[8], dd[8];
        load_tbl(tblL + (H0 + H1)*64, lo, dd);
        float g[NB];
#pragma unroll
        for (int i = 0; i < NB; ++i) g[i] = h1s[idx2L[i]*256 + tid];
        out[((size_t)img*COUT + t)*256 + tid] = lut_tree(lo, dd, g);
    }
}

extern "C" void kernel_launch(void* const* d_in, const int* in_sizes, int n_in,
                              void* d_out, int out_size, void* d_ws, size_t ws_size,
                              hipStream_t stream) {
    const float* x      = (const float*)d_in[0];
    const int*   idx0   = (const int*)  d_in[1];
    const float* table0 = (const float*)d_in[2];
    const int*   idx1   = (const int*)  d_in[3];
    const float* table1 = (const float*)d_in[4];
    const int*   idx2   = (const int*)  d_in[5];
    const float* table2 = (const float*)d_in[6];
    float* out = (float*)d_out;

    lutone_kernel<<<COUT * B_IMG, 256, 0, stream>>>(
        x, idx0, table0, idx1, table1, idx2, table2, out);
}